// Round 13
// baseline (79.240 us; speedup 1.0000x reference)
//
#include <hip/hip_runtime.h>
#include <math.h>

#define BB 32
#define CC 512      // = L (sequence length)
#define HW 4096
#define DM 32       // d_model
#define DI 32       // d_inner
#define DS 8        // d_state
#define KC 4        // conv kernel

#define NCH 16      // chunks per (b,dir)
#define CHL 32      // chunk length

__device__ __forceinline__ float siluf(float x) {
    return x / (1.0f + __expf(-x));
}
__device__ __forceinline__ float softplusf(float x) {
    float ax = fabsf(x);
    return fmaxf(x, 0.0f) + log1pf(__expf(-ax));
}

// ---- Kernel 1: FUSED pool + lin1 + LN + in_proj, wave-per-row (R10-proven, unchanged) ----
__global__ __launch_bounds__(256) void poolproj_kernel(
    const float* __restrict__ x,
    const float* __restrict__ lin1_w, const float* __restrict__ lin1_b,
    const float* __restrict__ ln1_g, const float* __restrict__ ln1_b,
    const float* __restrict__ in_proj_w, float* __restrict__ xz)
{
    __shared__ float sWp[64][33];   // in_proj_w padded
    int tid = threadIdx.x;
    for (int i = tid; i < 64 * DM; i += 256) sWp[i >> 5][i & 31] = in_proj_w[i];
    __syncthreads();                // only barrier; before any LDS read

    int wave = tid >> 6, lane = tid & 63;
    int row = blockIdx.x * 4 + wave;           // b*512 + c
    const float4* xp = reinterpret_cast<const float4*>(x + (size_t)row * HW);
    float s = 0.f, m = -INFINITY;
#pragma unroll
    for (int k = 0; k < 16; ++k) {
        float4 v = xp[k * 64 + lane];
        s += (v.x + v.y) + (v.z + v.w);
        m = fmaxf(m, fmaxf(fmaxf(v.x, v.y), fmaxf(v.z, v.w)));
    }
#pragma unroll
    for (int off = 1; off < 64; off <<= 1) {
        s += __shfl_xor(s, off);
        m = fmaxf(m, __shfl_xor(m, off));
    }
    float a = s * (1.0f / HW);
    int m_ = lane & 31;                        // lanes 32-63 duplicate 0-31
    float h = a * lin1_w[2 * m_] + m * lin1_w[2 * m_ + 1] + lin1_b[m_];
    float sum = h;
#pragma unroll
    for (int mask = 1; mask < 32; mask <<= 1) sum += __shfl_xor(sum, mask);
    float mean = sum * (1.0f / DM);
    float d = h - mean;
    float vs = d * d;
#pragma unroll
    for (int mask = 1; mask < 32; mask <<= 1) vs += __shfl_xor(vs, mask);
    float rs = rsqrtf(vs * (1.0f / DM) + 1e-5f);
    float hn = d * rs * ln1_g[m_] + ln1_b[m_];
    float acc = 0.f;
#pragma unroll
    for (int mm = 0; mm < DM; ++mm)
        acc += __shfl(hn, mm) * sWp[lane][mm];
    xz[((size_t)row << 6) + lane] = acc;
}

// ------- Kernel 2: BOTH-DIR conv + silu + proj(dt,B) + dt + scan PHASE 1 -> CARRIES ONLY -------
// grid = b x 16 orig-l tiles; block = 512 threads (dir = tid>>8). No u/dt/B/C global output.
__global__ __launch_bounds__(512) void convscan1_kernel(
    const float* __restrict__ xz,
    const float* __restrict__ conv_w_f, const float* __restrict__ conv_b_f,
    const float* __restrict__ xproj_w_f, const float* __restrict__ dtproj_w_f,
    const float* __restrict__ dtproj_b_f,
    const float* __restrict__ conv_w_r, const float* __restrict__ conv_b_r,
    const float* __restrict__ xproj_w_r, const float* __restrict__ dtproj_w_r,
    const float* __restrict__ dtproj_b_r,
    const float* __restrict__ A_log_f, const float* __restrict__ A_log_r,
    float* __restrict__ carrA, float* __restrict__ carrH)
{
    int bx = blockIdx.x;
    int b = bx >> 4, t = bx & 15;       // batch, orig l-tile
    int tid = threadIdx.x;
    int L0 = t * CHL;

    __shared__ float xt[32][41];        // [d][c], orig cols L0-3 .. L0+34 (38 used)
    __shared__ float xw_s[2][10][33];   // dt-rank(2) + B(8) rows only
    __shared__ float u_s[2][CHL][33];   // indexed by orig-rel l
    __shared__ float dt_s[2][CHL][33];
    __shared__ float B_s[2][CHL][9];
    __shared__ float dtr_s[2][CHL][2];

    // stage shared xz x-half tile with halo 3 both sides (zero outside sequence)
    for (int idx = tid; idx < 38 * 32; idx += 512) {
        int c = idx >> 5, dd = idx & 31;
        int col = L0 - 3 + c;
        float v = 0.f;
        if (col >= 0 && col < 512)
            v = xz[(((size_t)b * 512 + col) << 6) + dd];
        xt[dd][c] = v;
    }
    for (int idx = tid; idx < 2 * 10 * 32; idx += 512) {
        int dirw = idx >= 320;
        int r2 = idx - dirw * 320;
        const float* xw = dirw ? xproj_w_r : xproj_w_f;
        xw_s[dirw][r2 >> 5][r2 & 31] = xw[r2];
    }
    __syncthreads();

    // conv + silu, both dirs (orig-rel index l) — R8/R12-proven formulas
#pragma unroll
    for (int p = 0; p < 4; ++p) {
        int idx = p * 512 + tid;        // 0..2047
        int dd = idx & 31, l = (idx >> 5) & 31, dirw = idx >> 10;
        const float* cw2 = dirw ? conv_w_r : conv_w_f;
        const float* cb2 = dirw ? conv_b_r : conv_b_f;
        float acc = cb2[dd];
        if (dirw == 0) {
#pragma unroll
            for (int k = 0; k < KC; ++k) acc += cw2[dd * KC + k] * xt[dd][l + k];
        } else {
#pragma unroll
            for (int jj = 0; jj < KC; ++jj) acc += cw2[dd * KC + 3 - jj] * xt[dd][l + 3 + jj];
        }
        u_s[dirw][l][dd] = siluf(acc);
    }
    __syncthreads();

    // projections: 2 dirs x 10 outputs x 32 l = 640 (dtr + B only)
#pragma unroll
    for (int p = 0; p < 2; ++p) {
        int idx = p * 512 + tid;
        if (idx < 640) {
            int dirw = idx >= 320;
            int r2 = idx - dirw * 320;
            int o = r2 >> 5, l = r2 & 31;
            float acc = 0.f;
#pragma unroll
            for (int m_ = 0; m_ < 32; ++m_) acc += u_s[dirw][l][m_] * xw_s[dirw][o][m_];
            if (o < 2) dtr_s[dirw][l][o] = acc;
            else       B_s[dirw][l][o - 2] = acc;
        }
    }
    __syncthreads();

    // dt = softplus(dtproj)
#pragma unroll
    for (int p = 0; p < 4; ++p) {
        int idx = p * 512 + tid;
        int dd = idx & 31, l = (idx >> 5) & 31, dirw = idx >> 10;
        const float* dw2 = dirw ? dtproj_w_r : dtproj_w_f;
        const float* db2 = dirw ? dtproj_b_r : dtproj_b_f;
        float v = dtr_s[dirw][l][0] * dw2[dd * 2] + dtr_s[dirw][l][1] * dw2[dd * 2 + 1] + db2[dd];
        dt_s[dirw][l][dd] = softplusf(v);
    }
    __syncthreads();

    // phase-1 local scan: thread = (dir, d, n); scan order (dir1 traverses l reversed)
    {
        int dir = tid >> 8;
        int tid2 = tid & 255;
        int dd = tid2 >> 3, nn = tid2 & 7;
        int jc = dir ? (15 - t) : t;    // this dir's chunk id
        const float* Alog = dir ? A_log_r : A_log_f;
        float Aa = -__expf(Alog[tid2]);
        float ap = 1.f, h = 0.f;
#pragma unroll 4
        for (int sl = 0; sl < CHL; ++sl) {
            int ll = dir ? (CHL - 1 - sl) : sl;
            float dtv = dt_s[dir][ll][dd];
            float uu  = u_s[dir][ll][dd];
            float bm  = B_s[dir][ll][nn];
            float dA  = __expf(dtv * Aa);
            ap *= dA;
            h = dA * h + dtv * uu * bm;
        }
        size_t cidx = (((size_t)(b * 2 + dir) * NCH + jc) << 8) + tid2;
        carrA[cidx] = ap;
        carrH[cidx] = h;
    }
}

// ------- Kernel 3: RECOMPUTE conv/proj/dt from xz + carry combine + PHASE 3 + head -------
// grid = b x 16 orig-l tiles of 32; block = 512 threads. All scan inputs from LDS.
__global__ __launch_bounds__(512) void scan2final_kernel(
    const float* __restrict__ xz,
    const float* __restrict__ carrA, const float* __restrict__ carrH,
    const float* __restrict__ conv_w_f, const float* __restrict__ conv_b_f,
    const float* __restrict__ xproj_w_f, const float* __restrict__ dtproj_w_f,
    const float* __restrict__ dtproj_b_f,
    const float* __restrict__ conv_w_r, const float* __restrict__ conv_b_r,
    const float* __restrict__ xproj_w_r, const float* __restrict__ dtproj_w_r,
    const float* __restrict__ dtproj_b_r,
    const float* __restrict__ A_log_f, const float* __restrict__ D_f,
    const float* __restrict__ A_log_r, const float* __restrict__ D_r,
    const float* __restrict__ out_proj_w, const float* __restrict__ mnorm_g,
    const float* __restrict__ mnorm_b, const float* __restrict__ lin2_w,
    const float* __restrict__ lin2_b, float* __restrict__ out)
{
    int bx = blockIdx.x;
    int b = bx >> 4, t = bx & 15;       // batch, original l-tile
    int tid = threadIdx.x;
    int L0 = t * CHL;

    __shared__ float xt[32][41];        // [d][c], orig cols L0-3 .. L0+34 (38 used)
    __shared__ float xw_s[2][18][33];
    __shared__ float u_s[2][CHL][33];   // orig-rel l
    __shared__ float dt_s[2][CHL][33];
    __shared__ float B_s[2][CHL][9];
    __shared__ float C_s[2][CHL][9];
    __shared__ float dtr_s[2][CHL][2];
    __shared__ float y_s[2][CHL][33];
    __shared__ float comb_s[CHL][33];
    __shared__ float opw_s[DM][33];

    // stage xt + xproj weights + out_proj weights
    for (int idx = tid; idx < 38 * 32; idx += 512) {
        int c = idx >> 5, dd = idx & 31;
        int col = L0 - 3 + c;
        float v = 0.f;
        if (col >= 0 && col < 512)
            v = xz[(((size_t)b * 512 + col) << 6) + dd];
        xt[dd][c] = v;
    }
    for (int idx = tid; idx < 2 * 18 * 32; idx += 512) {
        int dirw = idx >= 576;
        int r2 = idx - dirw * 576;
        const float* xw = dirw ? xproj_w_r : xproj_w_f;
        xw_s[dirw][r2 >> 5][r2 & 31] = xw[r2];
    }
    for (int idx = tid; idx < DM * 32; idx += 512) opw_s[idx >> 5][idx & 31] = out_proj_w[idx];
    __syncthreads();

    // conv + silu, both dirs
#pragma unroll
    for (int p = 0; p < 4; ++p) {
        int idx = p * 512 + tid;        // 0..2047
        int dd = idx & 31, l = (idx >> 5) & 31, dirw = idx >> 10;
        const float* cw2 = dirw ? conv_w_r : conv_w_f;
        const float* cb2 = dirw ? conv_b_r : conv_b_f;
        float acc = cb2[dd];
        if (dirw == 0) {
#pragma unroll
            for (int k = 0; k < KC; ++k) acc += cw2[dd * KC + k] * xt[dd][l + k];
        } else {
#pragma unroll
            for (int jj = 0; jj < KC; ++jj) acc += cw2[dd * KC + 3 - jj] * xt[dd][l + 3 + jj];
        }
        u_s[dirw][l][dd] = siluf(acc);
    }
    __syncthreads();

    // projections: 2 dirs x 18 outputs x 32 l = 1152
#pragma unroll
    for (int p = 0; p < 3; ++p) {
        int idx = p * 512 + tid;
        if (idx < 1152) {
            int dirw = idx >= 576;
            int r2 = idx - dirw * 576;
            int o = r2 >> 5, l = r2 & 31;
            float acc = 0.f;
#pragma unroll
            for (int m_ = 0; m_ < 32; ++m_) acc += u_s[dirw][l][m_] * xw_s[dirw][o][m_];
            if (o < 2)       dtr_s[dirw][l][o] = acc;
            else if (o < 10) B_s[dirw][l][o - 2] = acc;
            else             C_s[dirw][l][o - 10] = acc;
        }
    }
    __syncthreads();

    // dt = softplus(dtproj)
#pragma unroll
    for (int p = 0; p < 4; ++p) {
        int idx = p * 512 + tid;
        int dd = idx & 31, l = (idx >> 5) & 31, dirw = idx >> 10;
        const float* dw2 = dirw ? dtproj_w_r : dtproj_w_f;
        const float* db2 = dirw ? dtproj_b_r : dtproj_b_f;
        float v = dtr_s[dirw][l][0] * dw2[dd * 2] + dtr_s[dirw][l][1] * dw2[dd * 2 + 1] + db2[dd];
        dt_s[dirw][l][dd] = softplusf(v);
    }
    __syncthreads();

    // carry combine + phase 3: thread = (dir, d, n), one n-state each
    {
        int dir = tid >> 8;
        int r = tid & 255;
        int d = r >> 3, n = r & 7;
        int bd = b * 2 + dir;
        int tt = dir ? (15 - t) : t;
        const float* Alog = dir ? A_log_r : A_log_f;
        const float* Dp   = dir ? D_r : D_f;
        float A  = -__expf(Alog[r]);
        float Dd = Dp[d];

        float h = 0.f;
        for (int g4 = 0; g4 < 4; ++g4) {
            int jbase = g4 * 4;
            if (jbase >= tt) break;
            float av[4], hv[4];
#pragma unroll
            for (int k = 0; k < 4; ++k) {
                int jj = jbase + k;
                int js = (jj < tt) ? jj : 0;
                size_t cb2 = (((size_t)bd * NCH + js) << 8) + r;
                av[k] = carrA[cb2];
                hv[k] = carrH[cb2];
            }
#pragma unroll
            for (int k = 0; k < 4; ++k)
                if (jbase + k < tt) h = av[k] * h + hv[k];
        }

#pragma unroll 4
        for (int sl = 0; sl < CHL; ++sl) {
            int ll = dir ? (CHL - 1 - sl) : sl;      // orig-rel index in scan order
            float dtv = dt_s[dir][ll][d];
            float uu  = u_s[dir][ll][d];
            float bm  = B_s[dir][ll][n];
            float cm  = C_s[dir][ll][n];
            h = __expf(dtv * A) * h + dtv * uu * bm;
            float py = h * cm;
            py += __shfl_xor(py, 1);
            py += __shfl_xor(py, 2);
            py += __shfl_xor(py, 4);
            if (n == 0) y_s[dir][ll][d] = py + Dd * uu;
        }
    }
    __syncthreads();

    // gate (z read directly from global; coalesced 128B per l-row)
    for (int idx = tid; idx < CHL * 32; idx += 512) {
        int l = idx >> 5, d = idx & 31;
        float z = xz[(((size_t)b * 512 + L0 + l) << 6) + 32 + d];
        comb_s[l][d] = 0.5f * (y_s[0][l][d] + y_s[1][l][d]) * siluf(z);
    }
    __syncthreads();

    // head: thread = (l, k), k owns oo=k and oo=k+16; 16-lane-group shuffles
    {
        int l = tid >> 4, k = tid & 15;
        float oa = 0.f, ob = 0.f;
#pragma unroll
        for (int d = 0; d < DI; ++d) {
            float c = comb_s[l][d];
            oa += c * opw_s[k][d];
            ob += c * opw_s[k + 16][d];
        }
        float sum = oa + ob;
#pragma unroll
        for (int mask = 1; mask < 16; mask <<= 1) sum += __shfl_xor(sum, mask);
        float mean = sum * (1.0f / DM);
        float da = oa - mean, db2 = ob - mean;
        float vs = da * da + db2 * db2;
#pragma unroll
        for (int mask = 1; mask < 16; mask <<= 1) vs += __shfl_xor(vs, mask);
        float rs = rsqrtf(vs * (1.0f / DM) + 1e-5f);
        float va = da * rs * mnorm_g[k] + mnorm_b[k];
        float vb = db2 * rs * mnorm_g[k + 16] + mnorm_b[k + 16];
        float sv = va * lin2_w[k] + vb * lin2_w[k + 16];
#pragma unroll
        for (int mask = 1; mask < 16; mask <<= 1) sv += __shfl_xor(sv, mask);
        if (k == 0) {
            float att = 1.0f / (1.0f + __expf(-(sv + lin2_b[0])));
            out[(size_t)b * 512 + L0 + l] = 0.25f * att + 0.875f;
        }
    }
}

extern "C" void kernel_launch(void* const* d_in, const int* in_sizes, int n_in,
                              void* d_out, int out_size, void* d_ws, size_t ws_size,
                              hipStream_t stream)
{
    const float* x         = (const float*)d_in[0];
    const float* lin1_w    = (const float*)d_in[1];
    const float* lin1_b    = (const float*)d_in[2];
    const float* ln1_g     = (const float*)d_in[3];
    const float* ln1_b     = (const float*)d_in[4];
    const float* in_proj_w = (const float*)d_in[5];
    const float* conv_w_f  = (const float*)d_in[6];
    const float* conv_b_f  = (const float*)d_in[7];
    const float* xproj_w_f = (const float*)d_in[8];
    const float* dtproj_w_f= (const float*)d_in[9];
    const float* dtproj_b_f= (const float*)d_in[10];
    const float* A_log_f   = (const float*)d_in[11];
    const float* D_f       = (const float*)d_in[12];
    const float* conv_w_r  = (const float*)d_in[13];
    const float* conv_b_r  = (const float*)d_in[14];
    const float* xproj_w_r = (const float*)d_in[15];
    const float* dtproj_w_r= (const float*)d_in[16];
    const float* dtproj_b_r= (const float*)d_in[17];
    const float* A_log_r   = (const float*)d_in[18];
    const float* D_r       = (const float*)d_in[19];
    const float* out_proj_w= (const float*)d_in[20];
    const float* mnorm_g   = (const float*)d_in[21];
    const float* mnorm_b   = (const float*)d_in[22];
    const float* lin2_w    = (const float*)d_in[23];
    const float* lin2_b    = (const float*)d_in[24];

    float* ws   = (float*)d_ws;
    float* xz   = ws;                          // 32*512*64 = 1048576  ([b][l][e])
    float* carrA= xz + 1048576;                // 64*16*256 = 262144
    float* carrH= carrA + 262144;              // 262144
    (void)ws_size; (void)in_sizes; (void)n_in; (void)out_size;

    poolproj_kernel<<<4096, 256, 0, stream>>>(x, lin1_w, lin1_b, ln1_g, ln1_b, in_proj_w, xz);
    convscan1_kernel<<<BB * NCH, 512, 0, stream>>>(
        xz, conv_w_f, conv_b_f, xproj_w_f, dtproj_w_f, dtproj_b_f,
        conv_w_r, conv_b_r, xproj_w_r, dtproj_w_r, dtproj_b_r,
        A_log_f, A_log_r, carrA, carrH);
    scan2final_kernel<<<BB * NCH, 512, 0, stream>>>(
        xz, carrA, carrH,
        conv_w_f, conv_b_f, xproj_w_f, dtproj_w_f, dtproj_b_f,
        conv_w_r, conv_b_r, xproj_w_r, dtproj_w_r, dtproj_b_r,
        A_log_f, D_f, A_log_r, D_r,
        out_proj_w, mnorm_g, mnorm_b, lin2_w, lin2_b, (float*)d_out);
}

// Round 14
// 76.430 us; speedup vs baseline: 1.0368x; 1.0368x over previous
//
#include <hip/hip_runtime.h>
#include <math.h>

#define BB 32
#define CC 512      // = L (sequence length)
#define HW 4096
#define DM 32       // d_model
#define DI 32       // d_inner
#define DS 8        // d_state
#define KC 4        // conv kernel

#define NCH 16      // chunks per (b,dir)
#define CHL 32      // chunk length

__device__ __forceinline__ float siluf(float x) {
    return x / (1.0f + __expf(-x));
}
__device__ __forceinline__ float softplusf(float x) {
    float ax = fabsf(x);
    return fmaxf(x, 0.0f) + log1pf(__expf(-ax));
}

// ---- Kernel 1: FUSED pool + lin1 + LN + in_proj, wave-per-row, barrier-free ----
// grid 4096 x 256. Wave w owns row blockIdx*4+w (row = b*512+l). One row per wave.
// After the 64-lane butterfly every lane holds s,m -> continue into hproj in-wave.
// xz layout [b][l][64]: coalesced 256B store per row. avg/mx never materialized.
__global__ __launch_bounds__(256) void poolproj_kernel(
    const float* __restrict__ x,
    const float* __restrict__ lin1_w, const float* __restrict__ lin1_b,
    const float* __restrict__ ln1_g, const float* __restrict__ ln1_b,
    const float* __restrict__ in_proj_w, float* __restrict__ xz)
{
    __shared__ float sWp[64][33];   // in_proj_w padded
    int tid = threadIdx.x;
    for (int i = tid; i < 64 * DM; i += 256) sWp[i >> 5][i & 31] = in_proj_w[i];
    __syncthreads();                // only barrier; before any LDS read

    int wave = tid >> 6, lane = tid & 63;
    int row = blockIdx.x * 4 + wave;           // b*512 + c
    const float4* xp = reinterpret_cast<const float4*>(x + (size_t)row * HW);
    float s = 0.f, m = -INFINITY;
#pragma unroll
    for (int k = 0; k < 16; ++k) {
        float4 v = xp[k * 64 + lane];
        s += (v.x + v.y) + (v.z + v.w);
        m = fmaxf(m, fmaxf(fmaxf(v.x, v.y), fmaxf(v.z, v.w)));
    }
#pragma unroll
    for (int off = 1; off < 64; off <<= 1) {
        s += __shfl_xor(s, off);
        m = fmaxf(m, __shfl_xor(m, off));
    }
    // all 64 lanes now hold identical s,m
    float a = s * (1.0f / HW);
    int m_ = lane & 31;                        // lanes 32-63 duplicate 0-31
    float h = a * lin1_w[2 * m_] + m * lin1_w[2 * m_ + 1] + lin1_b[m_];
    float sum = h;
#pragma unroll
    for (int mask = 1; mask < 32; mask <<= 1) sum += __shfl_xor(sum, mask);
    float mean = sum * (1.0f / DM);
    float d = h - mean;
    float vs = d * d;
#pragma unroll
    for (int mask = 1; mask < 32; mask <<= 1) vs += __shfl_xor(vs, mask);
    float rs = rsqrtf(vs * (1.0f / DM) + 1e-5f);
    float hn = d * rs * ln1_g[m_] + ln1_b[m_];
    // in_proj row e = lane: gather h[mm] from lane mm (<32) of this wave
    float acc = 0.f;
#pragma unroll
    for (int mm = 0; mm < DM; ++mm)
        acc += __shfl(hn, mm) * sWp[lane][mm];
    xz[((size_t)row << 6) + lane] = acc;       // coalesced 256B per row
}

// ------- Kernel 2: conv1d + silu + x_proj + dtproj + scan PHASE 1 (R7/R9-proven) -------
// grid = (b,dir) x 16 chunks of 32 scan positions; block = 256 threads. 16 waves/CU.
__global__ __launch_bounds__(256) void convscan1_kernel(
    const float* __restrict__ xz,
    const float* __restrict__ conv_w_f, const float* __restrict__ conv_b_f,
    const float* __restrict__ xproj_w_f, const float* __restrict__ dtproj_w_f,
    const float* __restrict__ dtproj_b_f,
    const float* __restrict__ conv_w_r, const float* __restrict__ conv_b_r,
    const float* __restrict__ xproj_w_r, const float* __restrict__ dtproj_w_r,
    const float* __restrict__ dtproj_b_r,
    const float* __restrict__ A_log_f, const float* __restrict__ A_log_r,
    float* __restrict__ u_g, float* __restrict__ dt_g,
    float* __restrict__ B_g, float* __restrict__ C_g,
    float* __restrict__ carrA, float* __restrict__ carrH)
{
    int bx = blockIdx.x;
    int bd = bx >> 4, j = bx & 15;      // (b,dir), chunk 0..15
    int b = bd >> 1, dir = bd & 1;
    int tid = threadIdx.x;
    const float* cw = dir ? conv_w_r : conv_w_f;
    const float* cb = dir ? conv_b_r : conv_b_f;
    const float* xw = dir ? xproj_w_r : xproj_w_f;
    const float* dw = dir ? dtproj_w_r : dtproj_w_f;
    const float* db = dir ? dtproj_b_r : dtproj_b_f;
    const float* Alog = dir ? A_log_r : A_log_f;

    __shared__ float xt[32][39];        // [d][t], scan cols j*32-3 .. j*32+31 (35 used)
    __shared__ float xw_s[18][33];
    __shared__ float u_s[CHL][33];
    __shared__ float dt_s[CHL][33];
    __shared__ float B_s[CHL][9];
    __shared__ float C_s[CHL][9];
    __shared__ float dtr_s[CHL][2];

    for (int idx = tid; idx < 35 * 32; idx += 256) {
        int t = idx >> 5, dd = idx & 31;
        int sidx = j * CHL - 3 + t;
        float v = 0.f;
        if (sidx >= 0) {
            int orig = dir ? (511 - sidx) : sidx;
            v = xz[(((size_t)b * 512 + orig) << 6) + dd];
        }
        xt[dd][t] = v;
    }
    for (int idx = tid; idx < 18 * 32; idx += 256)
        xw_s[idx >> 5][idx & 31] = xw[idx];
    __syncthreads();

    // conv + silu -> u_s  (thread = (l, 8-group), 4 d each)
    int l = tid >> 3, g8 = tid & 7;
#pragma unroll
    for (int i = 0; i < 4; ++i) {
        int dd = g8 * 4 + i;
        float acc = cb[dd];
#pragma unroll
        for (int k = 0; k < KC; ++k) acc += cw[dd * KC + k] * xt[dd][l + k];
        u_s[l][dd] = siluf(acc);
    }
    __syncthreads();

    // projections: 18 outputs per l (2 dt-rank, 8 B, 8 C)
    for (int o = g8; o < 18; o += 8) {
        float acc = 0.f;
#pragma unroll
        for (int m_ = 0; m_ < 32; ++m_) acc += u_s[l][m_] * xw_s[o][m_];
        if (o < 2) dtr_s[l][o] = acc;
        else if (o < 10) B_s[l][o - 2] = acc;
        else             C_s[l][o - 10] = acc;
    }
    __syncthreads();

    // dt = softplus(dtproj); coalesced global writes of u/dt/B/C
    size_t rowbase = ((size_t)bd * 512 + j * CHL) * 32;
    for (int idx = tid; idx < CHL * 32; idx += 256) {
        int ll = idx >> 5, dd = idx & 31;
        float v = dtr_s[ll][0] * dw[dd * 2] + dtr_s[ll][1] * dw[dd * 2 + 1] + db[dd];
        float sp = softplusf(v);
        dt_s[ll][dd] = sp;
        dt_g[rowbase + idx] = sp;
        u_g[rowbase + idx] = u_s[ll][dd];
    }
    size_t base8 = ((size_t)bd * 512 + j * CHL) * 8;
    if (tid < CHL * 8) {
        B_g[base8 + tid] = B_s[tid >> 3][tid & 7];
        C_g[base8 + tid] = C_s[tid >> 3][tid & 7];
    }
    __syncthreads();

    // phase-1 local scan: thread = (d, n)
    int dd = tid >> 3, nn = tid & 7;
    float Aa = -__expf(Alog[tid]);
    float ap = 1.f, h = 0.f;
#pragma unroll 4
    for (int sl = 0; sl < CHL; ++sl) {
        float dtv = dt_s[sl][dd];
        float uu  = u_s[sl][dd];
        float bm  = B_s[sl][nn];
        float dA  = __expf(dtv * Aa);
        ap *= dA;
        h = dA * h + dtv * uu * bm;
    }
    carrA[((size_t)bx << 8) + tid] = ap;
    carrH[((size_t)bx << 8) + tid] = h;
}

// ------- Kernel 3: carry combine + PHASE 3 + head, 512-thread blocks (R7-proven) -------
// grid = b x 16 orig-l tiles of 32; thread = (dir, d, n), one n-state each.
__global__ __launch_bounds__(512) void scan2final_kernel(
    const float* __restrict__ u_g, const float* __restrict__ dt_g,
    const float* __restrict__ B_g, const float* __restrict__ C_g,
    const float* __restrict__ carrA, const float* __restrict__ carrH,
    const float* __restrict__ A_log_f, const float* __restrict__ D_f,
    const float* __restrict__ A_log_r, const float* __restrict__ D_r,
    const float* __restrict__ xz,
    const float* __restrict__ out_proj_w, const float* __restrict__ mnorm_g,
    const float* __restrict__ mnorm_b, const float* __restrict__ lin2_w,
    const float* __restrict__ lin2_b, float* __restrict__ out)
{
    int bx = blockIdx.x;
    int b = bx >> 4, t = bx & 15;       // batch, original l-tile
    int tid = threadIdx.x;
    int L0 = t * CHL;

    __shared__ float u_s[2][CHL][33];
    __shared__ float dt_s[2][CHL][33];
    __shared__ float B_s[2][CHL][12];
    __shared__ float C_s[2][CHL][12];
    __shared__ float z_s[CHL][33];
    __shared__ float y_s[2][CHL][33];
    __shared__ float comb_s[CHL][33];
    __shared__ float opw_s[DM][33];

    // stage u/dt for both dirs' chunks covering this tile (coalesced over d)
    for (int idx = tid; idx < 2 * CHL * 32; idx += 512) {
        int dirw = idx >> 10;
        int r2 = idx & 1023;
        int sl = r2 >> 5, d = r2 & 31;
        int bd = b * 2 + dirw;
        int tc = dirw ? (15 - t) : t;
        size_t g = ((size_t)bd * 512 + tc * CHL + sl) * 32 + d;
        u_s[dirw][sl][d]  = u_g[g];
        dt_s[dirw][sl][d] = dt_g[g];
    }
    // stage B/C (512 elements each, one per thread)
    {
        int dirw = tid >> 8;
        int r2 = tid & 255;
        int sl = r2 >> 3, n = r2 & 7;
        int bd = b * 2 + dirw;
        int tc = dirw ? (15 - t) : t;
        size_t g = ((size_t)bd * 512 + tc * CHL + sl) * 8 + n;
        B_s[dirw][sl][n] = B_g[g];
        C_s[dirw][sl][n] = C_g[g];
    }
    // stage z rows + out_proj weights
    for (int idx = tid; idx < CHL * 32; idx += 512) {
        int l = idx >> 5, d = idx & 31;
        z_s[l][d] = xz[(((size_t)b * 512 + L0 + l) << 6) + 32 + d];
        opw_s[idx >> 5][d] = out_proj_w[idx];
    }
    __syncthreads();

    // carry combine + phase 3: thread = (dir, d, n)
    {
        int dir = tid >> 8;
        int r = tid & 255;
        int d = r >> 3, n = r & 7;
        int bd = b * 2 + dir;
        int tt = dir ? (15 - t) : t;
        const float* Alog = dir ? A_log_r : A_log_f;
        const float* Dp   = dir ? D_r : D_f;
        float A  = -__expf(Alog[r]);
        float Dd = Dp[d];

        float h = 0.f;
        for (int g4 = 0; g4 < 4; ++g4) {
            int jbase = g4 * 4;
            if (jbase >= tt) break;
            float av[4], hv[4];
#pragma unroll
            for (int k = 0; k < 4; ++k) {
                int jj = jbase + k;
                int js = (jj < tt) ? jj : 0;
                size_t cb2 = (((size_t)bd * NCH + js) << 8) + r;
                av[k] = carrA[cb2];
                hv[k] = carrH[cb2];
            }
#pragma unroll
            for (int k = 0; k < 4; ++k)
                if (jbase + k < tt) h = av[k] * h + hv[k];
        }

#pragma unroll 4
        for (int sl = 0; sl < CHL; ++sl) {
            float dtv = dt_s[dir][sl][d];
            float uu  = u_s[dir][sl][d];
            float bm  = B_s[dir][sl][n];
            float cm  = C_s[dir][sl][n];
            h = __expf(dtv * A) * h + dtv * uu * bm;
            float py = h * cm;
            py += __shfl_xor(py, 1);
            py += __shfl_xor(py, 2);
            py += __shfl_xor(py, 4);
            if (n == 0) {
                int ll = dir ? (CHL - 1 - sl) : sl;
                y_s[dir][ll][d] = py + Dd * uu;
            }
        }
    }
    __syncthreads();

    // gate
    for (int idx = tid; idx < CHL * 32; idx += 512) {
        int l = idx >> 5, d = idx & 31;
        comb_s[l][d] = 0.5f * (y_s[0][l][d] + y_s[1][l][d]) * siluf(z_s[l][d]);
    }
    __syncthreads();

    // head: thread = (l, k), k owns oo=k and oo=k+16; 16-lane-group shuffles
    {
        int l = tid >> 4, k = tid & 15;
        float oa = 0.f, ob = 0.f;
#pragma unroll
        for (int d = 0; d < DI; ++d) {
            float c = comb_s[l][d];
            oa += c * opw_s[k][d];
            ob += c * opw_s[k + 16][d];
        }
        float sum = oa + ob;
#pragma unroll
        for (int mask = 1; mask < 16; mask <<= 1) sum += __shfl_xor(sum, mask);
        float mean = sum * (1.0f / DM);
        float da = oa - mean, db2 = ob - mean;
        float vs = da * da + db2 * db2;
#pragma unroll
        for (int mask = 1; mask < 16; mask <<= 1) vs += __shfl_xor(vs, mask);
        float rs = rsqrtf(vs * (1.0f / DM) + 1e-5f);
        float va = da * rs * mnorm_g[k] + mnorm_b[k];
        float vb = db2 * rs * mnorm_g[k + 16] + mnorm_b[k + 16];
        float sv = va * lin2_w[k] + vb * lin2_w[k + 16];
#pragma unroll
        for (int mask = 1; mask < 16; mask <<= 1) sv += __shfl_xor(sv, mask);
        if (k == 0) {
            float att = 1.0f / (1.0f + __expf(-(sv + lin2_b[0])));
            out[(size_t)b * 512 + L0 + l] = 0.25f * att + 0.875f;
        }
    }
}

extern "C" void kernel_launch(void* const* d_in, const int* in_sizes, int n_in,
                              void* d_out, int out_size, void* d_ws, size_t ws_size,
                              hipStream_t stream)
{
    const float* x         = (const float*)d_in[0];
    const float* lin1_w    = (const float*)d_in[1];
    const float* lin1_b    = (const float*)d_in[2];
    const float* ln1_g     = (const float*)d_in[3];
    const float* ln1_b     = (const float*)d_in[4];
    const float* in_proj_w = (const float*)d_in[5];
    const float* conv_w_f  = (const float*)d_in[6];
    const float* conv_b_f  = (const float*)d_in[7];
    const float* xproj_w_f = (const float*)d_in[8];
    const float* dtproj_w_f= (const float*)d_in[9];
    const float* dtproj_b_f= (const float*)d_in[10];
    const float* A_log_f   = (const float*)d_in[11];
    const float* D_f       = (const float*)d_in[12];
    const float* conv_w_r  = (const float*)d_in[13];
    const float* conv_b_r  = (const float*)d_in[14];
    const float* xproj_w_r = (const float*)d_in[15];
    const float* dtproj_w_r= (const float*)d_in[16];
    const float* dtproj_b_r= (const float*)d_in[17];
    const float* A_log_r   = (const float*)d_in[18];
    const float* D_r       = (const float*)d_in[19];
    const float* out_proj_w= (const float*)d_in[20];
    const float* mnorm_g   = (const float*)d_in[21];
    const float* mnorm_b   = (const float*)d_in[22];
    const float* lin2_w    = (const float*)d_in[23];
    const float* lin2_b    = (const float*)d_in[24];

    float* ws   = (float*)d_ws;
    float* xz   = ws;                          // 32*512*64 = 1048576  ([b][l][e])
    float* u_g  = xz + 1048576;                // 1048576
    float* dt_g = u_g + 1048576;               // 1048576
    float* B_g  = dt_g + 1048576;              // 262144
    float* C_g  = B_g + 262144;                // 262144
    float* carrA= C_g + 262144;                // 64*16*256 = 262144
    float* carrH= carrA + 262144;              // 262144
    (void)ws_size; (void)in_sizes; (void)n_in; (void)out_size;

    poolproj_kernel<<<4096, 256, 0, stream>>>(x, lin1_w, lin1_b, ln1_g, ln1_b, in_proj_w, xz);
    convscan1_kernel<<<BB * 2 * NCH, 256, 0, stream>>>(
        xz, conv_w_f, conv_b_f, xproj_w_f, dtproj_w_f, dtproj_b_f,
        conv_w_r, conv_b_r, xproj_w_r, dtproj_w_r, dtproj_b_r,
        A_log_f, A_log_r, u_g, dt_g, B_g, C_g, carrA, carrH);
    scan2final_kernel<<<BB * NCH, 512, 0, stream>>>(
        u_g, dt_g, B_g, C_g, carrA, carrH,
        A_log_f, D_f, A_log_r, D_r, xz,
        out_proj_w, mnorm_g, mnorm_b, lin2_w, lin2_b, (float*)d_out);
}